// Round 13
// baseline (44.148 us; speedup 1.0000x reference)
//
#include <hip/hip_runtime.h>

// Problem constants (match reference)
#define BATCH 16
#define IMG_H 1024
#define IMG_W 1024
#define WORDS 16                              // 1024 cols / 64 bits
#define TOTAL_PX (BATCH * IMG_H * IMG_W)      // 16777216
#define TOTAL_WORDS (TOTAL_PX / 64)           // 262144 (2 MiB as u64)
typedef unsigned long long u64;
typedef unsigned u32x2 __attribute__((ext_vector_type(2)));

// stable BCE-with-logits: pe = max(x,0) - x*y + log1p(exp(-|x|))
//                            = max(sgn,0) + ln2*log2(1 + 2^(-|x|*log2e))
__device__ __forceinline__ float bce1(float x, bool y)
{
    unsigned xu = __float_as_uint(x);
    float sgn = __uint_as_float(xu ^ (y ? 0x80000000u : 0u));
    float a   = __uint_as_float(xu & 0x7fffffffu);
    float t   = __builtin_exp2f(a * -1.44269504088896340736f);
    float l2  = __builtin_log2f(1.0f + t);
    return fmaf(l2, 0.69314718055994530942f, fmaxf(sgn, 0.0f));
}

// async global->LDS, 16B per lane; lds dst = wave-uniform base + lane*16
__device__ __forceinline__ void g2l16(const float* g, float* l)
{
    __builtin_amdgcn_global_load_lds(
        (const __attribute__((address_space(1))) void*)g,
        (__attribute__((address_space(3))) void*)l,
        16, 0, 0);
}

// ===================== kernel 1: pack targets -> bitmask (proven) ============
#define PK_NT 256
#define PK_BLOCKS 8192
#define PK_WAVES (PK_NT / 64)                            // 4
#define GROUPS (TOTAL_WORDS / 4)                         // 65536
#define PK_ITERS (GROUPS / (PK_BLOCKS * PK_WAVES))       // 2

__global__ __launch_bounds__(PK_NT, 8)
void wbce_pack_kernel(const float* __restrict__ tgt, u64* __restrict__ pak)
{
    const int lane = threadIdx.x & 63;
    const int gw   = blockIdx.x * PK_WAVES + (threadIdx.x >> 6);
    #pragma unroll
    for (int i = 0; i < PK_ITERS; ++i) {
        int g = gw + i * (PK_BLOCKS * PK_WAVES);
        const float* p = tgt + (size_t)g * 256 + lane;
        float v0 = p[0], v1 = p[64], v2 = p[128], v3 = p[192];
        u64 m0 = __ballot(v0 > 0.5f);
        u64 m1 = __ballot(v1 > 0.5f);
        u64 m2 = __ballot(v2 > 0.5f);
        u64 m3 = __ballot(v3 > 0.5f);
        if (lane == 0) {
            ulonglong2* q = (ulonglong2*)(pak + (size_t)g * 4);
            q[0] = make_ulonglong2(m0, m1);
            q[1] = make_ulonglong2(m2, m3);
        }
    }
}

// ========== kernel 2: bitwise 9x9 morphology -> interleaved tbnd (proven) ====
#define MO_NT 256
__global__ __launch_bounds__(MO_NT, 8)
void wbce_morph_kernel(const u64* __restrict__ pak, uint4* __restrict__ tbnd)
{
    const int idx = blockIdx.x * MO_NT + threadIdx.x;    // word id [0, 262144)
    const int w   = idx & 15;
    const int row = (idx >> 4) & (IMG_H - 1);
    const int img = idx >> 14;
    const u64* ib = pak + (size_t)img * (IMG_H * WORDS);

    u64 d = 0ULL, e = ~0ULL, C = 0ULL;
    const int r0 = row >= 4 ? row - 4 : 0;               // OOB rows: neutral
    const int r1 = row <= IMG_H - 5 ? row + 4 : IMG_H - 1;
    for (int r = r0; r <= r1; ++r) {
        const u64* rp = ib + (size_t)r * WORDS;
        u64 c  = rp[w];
        u64 P  = (w > 0)  ? rp[w - 1] : 0ULL;            // OOB col: dilate fill 0
        u64 N  = (w < 15) ? rp[w + 1] : 0ULL;
        u64 Pe = (w > 0)  ? P : ~0ULL;                   // OOB col: erode fill 1
        u64 Ne = (w < 15) ? N : ~0ULL;
        u64 hd = c, he = c;
        #pragma unroll
        for (int s = 1; s <= 4; ++s) {
            hd |= (c >> s) | (N  << (64 - s));
            hd |= (c << s) | (P  >> (64 - s));
            he &= (c >> s) | (Ne << (64 - s));
            he &= (c << s) | (Pe >> (64 - s));
        }
        d |= hd;
        e &= he;
        if (r == row) C = c;
    }
    u64 bnd = d & ~e;
    tbnd[idx] = make_uint4((unsigned)C,         (unsigned)bnd,
                           (unsigned)(C >> 32), (unsigned)(bnd >> 32));
}

// ====== kernel 3: BCE via global_load_lds staging (register-free MLP) ========
// Block = 8192 logits (32KB LDS). 8 tbnd dwordx2 in one volatile asm, then
// 8 global_load_lds per wave (two 16KB halves). Counted vmcnt(4) + raw
// s_barrier double-buffer: consume half A while half B is still in flight.
#define BC_NT 256
#define BC_FLOATS 8192
#define BC_BLOCKS (TOTAL_PX / BC_FLOATS)                 // 2048

__global__ __launch_bounds__(BC_NT, 4)
void wbce_bce_kernel(const float* __restrict__ logits,
                     const uint2* __restrict__ tbnd2,    // uint4 viewed as uint2
                     float* __restrict__ partial)
{
    __shared__ float sX[BC_FLOATS];                      // 32 KB logits stage
    __shared__ float sRed[BC_NT / 64];
    const int tid = threadIdx.x, lane = tid & 63, wv = tid >> 6;
    const size_t blockFloat = (size_t)blockIdx.x * BC_FLOATS;

    // ---- tbnd side-words: 8 x dwordx2, one volatile asm (cannot be sunk).
    // uint2 idx = f4_global >> 3; per k: base + k*32 uint2 (256B offsets).
    const uint2* ta = tbnd2 + (size_t)blockIdx.x * 256 + (tid >> 3);
    u32x2 tb0, tb1, tb2, tb3, tb4, tb5, tb6, tb7;
    asm volatile(
        "global_load_dwordx2 %0, %8, off\n\t"
        "global_load_dwordx2 %1, %8, off offset:256\n\t"
        "global_load_dwordx2 %2, %8, off offset:512\n\t"
        "global_load_dwordx2 %3, %8, off offset:768\n\t"
        "global_load_dwordx2 %4, %8, off offset:1024\n\t"
        "global_load_dwordx2 %5, %8, off offset:1280\n\t"
        "global_load_dwordx2 %6, %8, off offset:1536\n\t"
        "global_load_dwordx2 %7, %8, off offset:1792"
        : "=&v"(tb0), "=&v"(tb1), "=&v"(tb2), "=&v"(tb3),
          "=&v"(tb4), "=&v"(tb5), "=&v"(tb6), "=&v"(tb7)
        : "v"(ta));

    // ---- stage half A [0,4096) then half B [4096,8192): 4+4 instr/wave ----
    #pragma unroll
    for (int j = 0; j < 4; ++j)
        g2l16(logits + blockFloat + wv * 1024 + j * 256 + lane * 4,
              sX + wv * 1024 + j * 256);
    #pragma unroll
    for (int j = 0; j < 4; ++j)
        g2l16(logits + blockFloat + 4096 + wv * 1024 + j * 256 + lane * 4,
              sX + 4096 + wv * 1024 + j * 256);

    // outstanding/wave: 8 tbnd + 4 A + 4 B = 16. vmcnt(4): tbnd + A done.
    asm volatile("s_waitcnt vmcnt(4)"
        : "+v"(tb0), "+v"(tb1), "+v"(tb2), "+v"(tb3) :: "memory");
    __builtin_amdgcn_sched_barrier(0);
    __builtin_amdgcn_s_barrier();                        // all waves: A landed

    const float4* sX4 = (const float4*)sX;
    const int sh = (tid & 7) * 4;                        // 4-bit field per f4
    float acc = 0.0f;

    #define CONSUME(k, tb)                                                    \
    do {                                                                      \
        float4 x4 = sX4[(k) * 256 + tid];                                     \
        unsigned tw = (tb).x, bw = (tb).y;                                    \
        const float xs[4] = {x4.x, x4.y, x4.z, x4.w};                         \
        _Pragma("unroll")                                                     \
        for (int j = 0; j < 4; ++j) {                                         \
            unsigned tbit = (tw >> (sh + j)) & 1u;                            \
            unsigned bbit = (bw >> (sh + j)) & 1u;                            \
            unsigned xu   = __float_as_uint(xs[j]);                           \
            float sgn = __uint_as_float(xu ^ (tbit << 31));                   \
            float av  = __uint_as_float(xu & 0x7fffffffu);                    \
            float t   = __builtin_exp2f(av * -1.44269504088896340736f);       \
            float l2  = __builtin_log2f(1.0f + t);                            \
            float pe  = fmaf(l2, 0.69314718055994530942f, fmaxf(sgn, 0.0f));  \
            float wg  = fmaf((float)bbit, 2.0f, 1.0f);  /* BOUNDARY_WEIGHT=3*/\
            acc = fmaf(wg, pe, acc);                                          \
        }                                                                     \
    } while (0)

    CONSUME(0, tb0); CONSUME(1, tb1); CONSUME(2, tb2); CONSUME(3, tb3);

    asm volatile("s_waitcnt vmcnt(0)"
        : "+v"(tb4), "+v"(tb5), "+v"(tb6), "+v"(tb7) :: "memory");
    __builtin_amdgcn_sched_barrier(0);
    __builtin_amdgcn_s_barrier();                        // all waves: B landed

    CONSUME(4, tb4); CONSUME(5, tb5); CONSUME(6, tb6); CONSUME(7, tb7);
    #undef CONSUME

    // ---- wave64 shuffle tree, cross-wave via LDS, one partial per block ----
    #pragma unroll
    for (int off = 32; off > 0; off >>= 1)
        acc += __shfl_down(acc, off, 64);
    if (lane == 0) sRed[wv] = acc;
    __syncthreads();
    if (tid == 0) {
        float s = 0.0f;
        #pragma unroll
        for (int i = 0; i < BC_NT / 64; ++i) s += sRed[i];
        partial[blockIdx.x] = s;
    }
}

// ====== kernel 4: final reduce of 2048 partials -> mean ======
#define FR_NT 512
__global__ __launch_bounds__(FR_NT, 1)
void wbce_final_kernel(const float* __restrict__ partial, float* __restrict__ out)
{
    __shared__ float sRed[FR_NT / 64];
    const int tid = threadIdx.x;
    float4 a = ((const float4*)partial)[tid];            // 512 float4 = 2048
    float acc = (a.x + a.y) + (a.z + a.w);
    #pragma unroll
    for (int off = 32; off > 0; off >>= 1)
        acc += __shfl_down(acc, off, 64);
    if ((tid & 63) == 0) sRed[tid >> 6] = acc;
    __syncthreads();
    if (tid == 0) {
        float s = 0.0f;
        #pragma unroll
        for (int i = 0; i < FR_NT / 64; ++i) s += sRed[i];
        out[0] = s * (1.0f / 16777216.0f);               // mean: 1/2^24 exact
    }
}

extern "C" void kernel_launch(void* const* d_in, const int* in_sizes, int n_in,
                              void* d_out, int out_size, void* d_ws, size_t ws_size,
                              hipStream_t stream) {
    const float* logits  = (const float*)d_in[0];
    const float* targets = (const float*)d_in[1];
    float* out = (float*)d_out;

    // scratch: pak 2 MiB | tbnd 4 MiB | partial 8 KiB
    char* ws = (char*)d_ws;
    u64*   pak     = (u64*)ws;
    uint4* tbnd    = (uint4*)(ws + (2u << 20));
    float* partial = (float*)(ws + (6u << 20));

    // 1) pack targets into bitmask words (proven ~4.6-4.9 TB/s)
    wbce_pack_kernel<<<dim3(PK_BLOCKS), dim3(PK_NT), 0, stream>>>(targets, pak);

    // 2) bitwise 9x9 morphology -> interleaved {target,boundary} words
    wbce_morph_kernel<<<dim3(TOTAL_WORDS / MO_NT), dim3(MO_NT), 0, stream>>>(pak, tbnd);

    // 3) BCE: logits staged via global_load_lds (no VGPR round-trip)
    wbce_bce_kernel<<<dim3(BC_BLOCKS), dim3(BC_NT), 0, stream>>>(
        logits, (const uint2*)tbnd, partial);

    // 4) final reduce -> out[0] (plain store; no zeroing needed anywhere)
    wbce_final_kernel<<<dim3(1), dim3(FR_NT), 0, stream>>>(partial, out);
}